// Round 4
// baseline (162.586 us; speedup 1.0000x reference)
//
#include <hip/hip_runtime.h>
#include <cstdint>
#include <cmath>

#define B_ 2
#define N_ 4096
#define D_ 128
#define H_ 16
#define DQK_ 64
#define DV_ 256

typedef float    f4_t __attribute__((ext_vector_type(4)));
typedef _Float16 h4_t __attribute__((ext_vector_type(4)));
typedef _Float16 h8_t __attribute__((ext_vector_type(8)));

__device__ __forceinline__ float sigmoidf_(float z) { return 1.f/(1.f + expf(-z)); }
__device__ __forceinline__ float siluf_(float z)    { return z/(1.f + expf(-z)); }

// ---------------- EMA: s[t] = q*s[t-1] + a*exp[h,d]*x[t], chunked scan ----------------
// grid 1024 = 2(b) * 64(chunk) * 8(dgroup); block 256 = 16h x 16d. Also emits xh (f16 x).
__global__ void ema_phase1(const float* __restrict__ x, const float* __restrict__ expansion,
                           const float* __restrict__ alphas, const float* __restrict__ dampen,
                           float* __restrict__ F, _Float16* __restrict__ xh) {
  int bid = blockIdx.x;
  int dg = bid & 7, c = (bid >> 3) & 63, b = bid >> 9;
  int h = threadIdx.x & 15, dl = threadIdx.x >> 4;
  int d = dg*16 + dl;
  float a  = sigmoidf_(alphas[h]);
  float dm = sigmoidf_(dampen[h]);
  float q  = (1.f - a)*dm;
  float coef = a * expansion[h*D_ + d];
  __shared__ float xs[64][16];
  {
    int e = threadIdx.x;                 // 1024 floats / 256 thr = 1 float4 each
    int t = e >> 2, seg = e & 3;
    const float* xp = x + ((size_t)b*N_ + c*64 + t)*D_ + dg*16 + seg*4;
    f4_t v = *(const f4_t*)xp;
    *(f4_t*)&xs[t][seg*4] = v;
    h4_t hv;
#pragma unroll
    for (int j = 0; j < 4; ++j) hv[j] = (_Float16)v[j];
    *(h4_t*)(xh + ((size_t)b*N_ + c*64 + t)*D_ + dg*16 + seg*4) = hv;
  }
  __syncthreads();
  float s = 0.f;
#pragma unroll
  for (int t = 0; t < 64; ++t) s = fmaf(q, s, coef*xs[t][dl]);
  F[(((size_t)b*H_ + h)*D_ + d)*64 + c] = s;
}

// grid 16 x 256 = 4096 threads = one per (b,h,d)
__global__ void ema_carry(const float* __restrict__ F, const float* __restrict__ alphas,
                          const float* __restrict__ dampen, float* __restrict__ carry) {
  int idx = blockIdx.x*256 + threadIdx.x;     // (b*16+h)*128 + d
  int h = (idx >> 7) & 15;
  float a  = sigmoidf_(alphas[h]);
  float dm = sigmoidf_(dampen[h]);
  float q  = (1.f - a)*dm;
  float qL = q;
#pragma unroll
  for (int i = 0; i < 6; ++i) qL *= qL;       // q^64
  const float* Fp = F + (size_t)idx*64;
  float* cp = carry + (size_t)idx*64;
  float s = 0.f;
  for (int cc = 0; cc < 64; ++cc) { cp[cc] = s; s = fmaf(qL, s, Fp[cc]); }
}

// same grid as phase1; fuses reduction over h into ema[b,t,d] (f32 + f16 copies)
__global__ void ema_phase2(const float* __restrict__ x, const float* __restrict__ expansion,
                           const float* __restrict__ reduction,
                           const float* __restrict__ alphas, const float* __restrict__ dampen,
                           const float* __restrict__ carry, float* __restrict__ ema,
                           _Float16* __restrict__ emah) {
  int bid = blockIdx.x;
  int dg = bid & 7, c = (bid >> 3) & 63, b = bid >> 9;
  int h = threadIdx.x & 15, dl = threadIdx.x >> 4;
  int d = dg*16 + dl;
  float a  = sigmoidf_(alphas[h]);
  float dm = sigmoidf_(dampen[h]);
  float q  = (1.f - a)*dm;
  float coef = a * expansion[h*D_ + d];
  float red  = reduction[h*D_ + d];
  __shared__ float xs[64][16];
  {
    int e = threadIdx.x;
    int t = e >> 2, seg = e & 3;
    const float* xp = x + ((size_t)b*N_ + c*64 + t)*D_ + dg*16 + seg*4;
    *(f4_t*)&xs[t][seg*4] = *(const f4_t*)xp;
  }
  __syncthreads();
  float s = carry[(((size_t)b*H_ + h)*D_ + d)*64 + c];
  for (int t = 0; t < 64; ++t) {
    s = fmaf(q, s, coef*xs[t][dl]);
    float v = red * s;
    v += __shfl_xor(v, 1); v += __shfl_xor(v, 2);
    v += __shfl_xor(v, 4); v += __shfl_xor(v, 8);
    if (h == 0) {
      size_t o = ((size_t)b*N_ + c*64 + t)*D_ + d;
      ema[o] = v;
      emah[o] = (_Float16)v;
    }
  }
}

// ---------------- rel-pos bias lookup table: bias[delta] ----------------
__global__ void bias_table(const float* __restrict__ rel_table, float* __restrict__ biasT) {
  int r = blockIdx.x*256 + threadIdx.x;       // 0..4095
  int bucket;
  if (r < 16) bucket = r;
  else {
    double v = log((double)r / 16.0) / log(8.0) * 16.0;
    bucket = 16 + (int)v;
    if (bucket > 31) bucket = 31;
  }
  biasT[r] = rel_table[bucket] * 8.0f;        // * sqrt(DQK)
}

// ---------------- weight prep: Wt[832][128] f16 (transposed concat), bcat[832] ----------------
__global__ void prep_weights(const float* __restrict__ Wqk, const float* __restrict__ Wv,
                             const float* __restrict__ Wr, const float* __restrict__ Wu,
                             const float* __restrict__ Wh,
                             const float* __restrict__ bqk, const float* __restrict__ bv,
                             const float* __restrict__ br, const float* __restrict__ bu,
                             const float* __restrict__ bh,
                             _Float16* __restrict__ Wt, float* __restrict__ bcat) {
  int idx = blockIdx.x*256 + threadIdx.x;     // 832*128
  if (idx >= 832*128) return;
  int c = idx >> 7, d = idx & 127;
  const float* W; const float* bias; int ncol, cl;
  if (c < 64)       { W=Wqk; bias=bqk; ncol=64;  cl=c; }
  else if (c < 320) { W=Wv;  bias=bv;  ncol=256; cl=c-64; }
  else if (c < 576) { W=Wr;  bias=br;  ncol=256; cl=c-320; }
  else if (c < 704) { W=Wu;  bias=bu;  ncol=128; cl=c-576; }
  else              { W=Wh;  bias=bh;  ncol=128; cl=c-704; }
  Wt[idx] = (_Float16)W[d*ncol + cl];
  if (d == 0) bcat[c] = bias[cl];
}

// Uht[c][k] = Uh[k][c] as f16.  grid 128 x 256
__global__ void prep_uh(const float* __restrict__ Uh, _Float16* __restrict__ Uht) {
  int idx = blockIdx.x*256 + threadIdx.x;     // 32768 = 256k x 128c
  int k = idx >> 7, c = idx & 127;
  Uht[(size_t)c*256 + k] = (_Float16)Uh[idx];
}

// ---------------- fused linears as MFMA GEMM: [8192 x 128] @ [128 x 832] ----------------
// grid = 128 rowtiles * 13 slabs, block 256 = 4 waves; wave w -> rows w*16.
__global__ __launch_bounds__(256) void linear_mfma(
    const _Float16* __restrict__ emah, const _Float16* __restrict__ xh,
    const _Float16* __restrict__ Wt, const float* __restrict__ bcat,
    const float* __restrict__ gamma, const float* __restrict__ beta,
    _Float16* __restrict__ qh, _Float16* __restrict__ kh, _Float16* __restrict__ vT,
    float* __restrict__ resetb, float* __restrict__ updateb, float* __restrict__ hemab) {
  int slab = blockIdx.x % 13, rt = blockIdx.x / 13;
  int tid = threadIdx.x;
  int lane = tid & 63, w = tid >> 6;
  int lr = lane & 15, lg = lane >> 4;
  int mode = (slab==0)?0:(slab<5)?1:(slab<9)?2:(slab<11)?3:4;
  const _Float16* src = (mode==1) ? xh : emah;
  __shared__ _Float16 As[64][136];
  __shared__ _Float16 Ws[64][136];
  {
    const h8_t* s8 = (const h8_t*)(src + (size_t)rt*64*D_);
#pragma unroll
    for (int i = 0; i < 4; ++i) {
      int idx = tid + i*256;
      int row = idx >> 4, seg = idx & 15;
      *(h8_t*)&As[row][seg*8] = s8[idx];
    }
    const h8_t* w8 = (const h8_t*)(Wt + (size_t)slab*64*D_);
#pragma unroll
    for (int i = 0; i < 4; ++i) {
      int idx = tid + i*256;
      int row = idx >> 4, seg = idx & 15;
      *(h8_t*)&Ws[row][seg*8] = w8[idx];
    }
  }
  __syncthreads();
  h4_t af[8];
#pragma unroll
  for (int ks = 0; ks < 8; ++ks) af[ks] = *(const h4_t*)&As[w*16 + lr][ks*16 + lg*4];
  int row0 = rt*64 + w*16 + lg*4;              // + r
#pragma unroll
  for (int ns = 0; ns < 4; ++ns) {
    f4_t acc = (f4_t){0.f,0.f,0.f,0.f};
#pragma unroll
    for (int ks = 0; ks < 8; ++ks) {
      h4_t bf = *(const h4_t*)&Ws[ns*16 + lr][ks*16 + lg*4];
      acc = __builtin_amdgcn_mfma_f32_16x16x16f16(af[ks], bf, acc, 0, 0, 0);
    }
    int c = slab*64 + ns*16 + lr;
    float bias = bcat[c];
    if (mode == 0) {
      float g0 = gamma[c], g1 = gamma[64+c], be0 = beta[c], be1 = beta[64+c];
#pragma unroll
      for (int r = 0; r < 4; ++r) {
        float qk = siluf_(acc[r] + bias);
        size_t row = row0 + r;
        qh[row*DQK_ + c] = (_Float16)(qk*g0 + be0);
        kh[row*DQK_ + c] = (_Float16)(qk*g1 + be1);
      }
    } else if (mode == 1) {
      int cl = c - 64;
      int bb = row0 >> 12, rl = row0 & 4095;
      h4_t vv;
#pragma unroll
      for (int r = 0; r < 4; ++r) vv[r] = (_Float16)siluf_(acc[r] + bias);
      *(h4_t*)&vT[((size_t)bb*DV_ + cl)*N_ + rl] = vv;
    } else if (mode == 2) {
      int cl = c - 320;
#pragma unroll
      for (int r = 0; r < 4; ++r) resetb[(size_t)(row0 + r)*DV_ + cl] = siluf_(acc[r] + bias);
    } else if (mode == 3) {
      int cl = c - 576;
#pragma unroll
      for (int r = 0; r < 4; ++r) updateb[(size_t)(row0 + r)*D_ + cl] = sigmoidf_(acc[r] + bias);
    } else {
      int cl = c - 704;
#pragma unroll
      for (int r = 0; r < 4; ++r) hemab[(size_t)(row0 + r)*D_ + cl] = acc[r] + bias;
    }
  }
}

// ---------------- attention: laplacian(QK^T/n + bias[i-j]) @ V, causal ----------------
// grid 2048 = 64(it, largest-first) x 8(jsplit) x 2(dvhalf) x 2(b). block 256 = 4 waves.
// Reg-staged double-buffered LDS (XOR chunk swizzle), one barrier per j-tile.
// Swapped MFMA: S^T = mfma(K, Q) puts P directly in the PV A-fragment layout.
__global__ __launch_bounds__(256) void attn_kernel(
    const _Float16* __restrict__ qh, const _Float16* __restrict__ kh,
    const _Float16* __restrict__ vT, const float* __restrict__ biasT,
    float* __restrict__ attnp) {
  int bid = blockIdx.x;
  int it  = 63 - (bid >> 5);
  int s   = bid & 7;
  int dvh = (bid >> 3) & 1;
  int b   = (bid >> 4) & 1;
  int njt = it + 1;
  int nblk = (njt + 7) >> 3;
  if (s >= nblk) return;
  int jlo = s*8, jhi = min(jlo + 8, njt);
  int q_ = it >> 3, r_ = it & 7;
  int slot = 4*q_*(q_+1) + r_*(q_+1) + s;       // compact partial index (288 per b,dvh)
  int i0 = it * 64;
  int tid = threadIdx.x;
  int lane = tid & 63, w = tid >> 6;
  int lr = lane & 15, lg = lane >> 4;

  __shared__ char lds[2][24576];                // per buf: K 8KB @0, V 16KB @8192

  const _Float16* kbase = kh + (size_t)b*N_*DQK_;
  const _Float16* vbase = vT + ((size_t)b*DV_ + dvh*128)*(size_t)N_;

  h4_t qf[4];
  const _Float16* qp = qh + ((size_t)b*N_ + i0 + w*16 + lr)*DQK_;
#pragma unroll
  for (int ks = 0; ks < 4; ++ks) qf[ks] = *(const h4_t*)(qp + ks*16 + lg*4);

  f4_t accO[8];
#pragma unroll
  for (int i = 0; i < 8; ++i) accO[i] = (f4_t){0.f,0.f,0.f,0.f};

  h8_t kreg[2], vreg[4];

#define ISSUE_(J0) { \
  _Pragma("unroll") for (int i = 0; i < 2; ++i) { \
    int idx = tid + i*256; int r = idx>>3, ss = idx&7; \
    kreg[i] = *(const h8_t*)(kbase + (size_t)((J0) + r)*DQK_ + ss*8); } \
  _Pragma("unroll") for (int i = 0; i < 4; ++i) { \
    int idx = tid + i*256; int r = idx>>3, ss = idx&7; \
    vreg[i] = *(const h8_t*)(vbase + (size_t)r*N_ + (J0) + ss*8); } }

#define COMMIT_(BUF) { \
  char* buf_ = (BUF); \
  _Pragma("unroll") for (int i = 0; i < 2; ++i) { \
    int idx = tid + i*256; int r = idx>>3, ss = idx&7; \
    *(h8_t*)(buf_ + r*128 + ((ss ^ (r&7))<<4)) = kreg[i]; } \
  _Pragma("unroll") for (int i = 0; i < 4; ++i) { \
    int idx = tid + i*256; int r = idx>>3, ss = idx&7; \
    *(h8_t*)(buf_ + 8192 + r*128 + ((ss ^ (r&7))<<4)) = vreg[i]; } }

  ISSUE_(jlo*64); COMMIT_(lds[0]);
  __syncthreads();
  int cur = 0;
  for (int jt = jlo; jt < jhi; ++jt) {
    int j0 = jt*64;
    bool more = (jt+1 < jhi);
    if (more) ISSUE_((jt+1)*64);                // overlap next loads with compute
    const char* kb = lds[cur];
    const char* vb = lds[cur] + 8192;
#pragma unroll
    for (int ns = 0; ns < 4; ++ns) {
      // S^T block: rows j, cols i  (A = K rows, B = Q^T)
      f4_t accS = (f4_t){0.f,0.f,0.f,0.f};
#pragma unroll
      for (int ks = 0; ks < 4; ++ks) {
        int jr = ns*16 + lr;
        h4_t kf = *(const h4_t*)(kb + jr*128 + (((2*ks + (lg>>1)) ^ (lr&7))<<4) + (lg&1)*8);
        accS = __builtin_amdgcn_mfma_f32_16x16x16f16(kf, qf[ks], accS, 0, 0, 0);
      }
      int jbase = j0 + ns*16 + lg*4;            // + r
      int irow  = i0 + w*16 + lr;
      h4_t pa;
#pragma unroll
      for (int r = 0; r < 4; ++r) {
        int delta = irow - (jbase + r);
        int dd = delta < 0 ? 0 : delta;
        float z = accS[r]*(1.f/4096.f) + biasT[dd];
        float pv = 0.5f*(1.f + erff((z - 0.70710678f)*0.79788456f));
        pa[r] = (_Float16)(delta < 0 ? 0.f : pv);
      }
      // O(half) += P(:, this 16-j-slice) @ V(this 16-j-slice, dv half)
#pragma unroll
      for (int ns2 = 0; ns2 < 8; ++ns2) {
        int vr = ns2*16 + lr;
        h4_t vf = *(const h4_t*)(vb + vr*128 + (((2*ns + (lg>>1)) ^ (lr&7))<<4) + (lg&1)*8);
        accO[ns2] = __builtin_amdgcn_mfma_f32_16x16x16f16(pa, vf, accO[ns2], 0, 0, 0);
      }
    }
    if (more) COMMIT_(lds[cur^1]);              // write next tile into other buffer
    __syncthreads();
    cur ^= 1;
  }

  float* op = attnp + ((size_t)((b*2 + dvh)*288) + slot)*8192;
#pragma unroll
  for (int ns2 = 0; ns2 < 8; ++ns2) {
#pragma unroll
    for (int r = 0; r < 4; ++r) {
      op[(size_t)(w*16 + lg*4 + r)*128 + ns2*16 + lr] = accO[ns2][r];
    }
  }
#undef ISSUE_
#undef COMMIT_
}

// gatedh = (sum of valid attn partials) * reset, cast to f16
__global__ void combine_gated(const float* __restrict__ attnp, const float* __restrict__ resetb,
                              _Float16* __restrict__ gatedh) {
  size_t fi = (size_t)blockIdx.x*256 + threadIdx.x;   // f4 index over 8192*256
  int c4 = (int)(fi & 63);                            // f4-chunk within 256 cols
  int rr = (int)(fi >> 6);
  int b = rr >> 12, n = rr & 4095;
  int it = n >> 6, rowLocal = n & 63;
  int q_ = it >> 3, r_ = it & 7;
  int nblk = q_ + 1;
  int base = 4*q_*(q_+1) + r_*(q_+1);
  int dvh = c4 >> 5, cl4 = c4 & 31;
  const f4_t* ap = (const f4_t*)(attnp
      + (((size_t)((b*2 + dvh)*288) + base)*64 + rowLocal)*128);
  f4_t acc = (f4_t){0.f,0.f,0.f,0.f};
  for (int s = 0; s < nblk; ++s)
    acc += ap[(size_t)s*2048 + cl4];
  f4_t rg = ((const f4_t*)resetb)[fi];
  f4_t g = acc * rg;
  h4_t hg;
#pragma unroll
  for (int j = 0; j < 4; ++j) hg[j] = (_Float16)g[j];
  *(h4_t*)(gatedh + fi*4) = hg;
}

// ---------------- final: H = silu(hemab + gated@Uh); out = u*H + (1-u)*x ----------------
// MFMA GEMM [8192 x 256] @ [256 x 128]. grid 256 = 128 rowtiles x 2 colslabs.
// block 256 = 4 waves; K staged in 2 chunks of 128.
__global__ __launch_bounds__(256) void final_mfma(
    const _Float16* __restrict__ gatedh, const _Float16* __restrict__ Uht,
    const float* __restrict__ hemab, const float* __restrict__ updateb,
    const float* __restrict__ x, float* __restrict__ out) {
  int rt = blockIdx.x >> 1, cs = blockIdx.x & 1;
  int tid = threadIdx.x;
  int lane = tid & 63, w = tid >> 6;
  int lr = lane & 15, lg = lane >> 4;
  int row0 = rt*64, c0 = cs*64;
  __shared__ _Float16 As[64][136];
  __shared__ _Float16 Ws[64][136];
  f4_t acc[4];
#pragma unroll
  for (int ns = 0; ns < 4; ++ns) acc[ns] = (f4_t){0.f,0.f,0.f,0.f};
#pragma unroll
  for (int kc = 0; kc < 2; ++kc) {
    __syncthreads();
#pragma unroll
    for (int i = 0; i < 4; ++i) {
      int idx = tid + i*256;
      int row = idx >> 4, seg = idx & 15;
      *(h8_t*)&As[row][seg*8] =
          *(const h8_t*)(gatedh + (size_t)(row0 + row)*DV_ + kc*128 + seg*8);
      *(h8_t*)&Ws[row][seg*8] =
          *(const h8_t*)(Uht + (size_t)(c0 + row)*DV_ + kc*128 + seg*8);
    }
    __syncthreads();
    h4_t af[8];
#pragma unroll
    for (int ks = 0; ks < 8; ++ks) af[ks] = *(const h4_t*)&As[w*16 + lr][ks*16 + lg*4];
#pragma unroll
    for (int ns = 0; ns < 4; ++ns) {
#pragma unroll
      for (int ks = 0; ks < 8; ++ks) {
        h4_t bf = *(const h4_t*)&Ws[ns*16 + lr][ks*16 + lg*4];
        acc[ns] = __builtin_amdgcn_mfma_f32_16x16x16f16(af[ks], bf, acc[ns], 0, 0, 0);
      }
    }
  }
  int orow = row0 + w*16 + lg*4;               // + r
#pragma unroll
  for (int ns = 0; ns < 4; ++ns) {
    int col = c0 + ns*16 + lr;
#pragma unroll
    for (int r = 0; r < 4; ++r) {
      size_t o = (size_t)(orow + r)*D_ + col;
      float z = acc[ns][r] + hemab[o];
      float Hv = siluf_(z);
      float u  = updateb[o];
      out[o] = u*Hv + (1.f - u)*x[o];
    }
  }
}

extern "C" void kernel_launch(void* const* d_in, const int* in_sizes, int n_in,
                              void* d_out, int out_size, void* d_ws, size_t ws_size,
                              hipStream_t stream) {
  (void)in_sizes; (void)n_in; (void)out_size; (void)ws_size;
  const float* x         = (const float*)d_in[0];
  const float* expansion = (const float*)d_in[1];
  const float* reduction = (const float*)d_in[2];
  const float* alphas    = (const float*)d_in[3];
  const float* dampen    = (const float*)d_in[4];
  const float* Wqk       = (const float*)d_in[5];
  const float* bqk       = (const float*)d_in[6];
  const float* gamma     = (const float*)d_in[7];
  const float* beta      = (const float*)d_in[8];
  const float* Wv        = (const float*)d_in[9];
  const float* bv        = (const float*)d_in[10];
  const float* rel_table = (const float*)d_in[11];
  const float* Wr        = (const float*)d_in[12];
  const float* br        = (const float*)d_in[13];
  const float* Wu        = (const float*)d_in[14];
  const float* bu        = (const float*)d_in[15];
  const float* Wh        = (const float*)d_in[16];
  const float* Uh        = (const float*)d_in[17];
  const float* bh        = (const float*)d_in[18];
  float* out = (float*)d_out;

  char* p = (char*)d_ws;
  size_t off = 0;
  auto alloc = [&](size_t bytes) -> char* {
    char* r = p + off;
    off += (bytes + 255) & ~(size_t)255;
    return r;
  };
  float*    F      = (float*)alloc((size_t)B_*H_*D_*64*4);
  float*    carry  = (float*)alloc((size_t)B_*H_*D_*64*4);
  float*    ema    = (float*)alloc((size_t)B_*N_*D_*4);
  _Float16* emah   = (_Float16*)alloc((size_t)B_*N_*D_*2);
  _Float16* xh     = (_Float16*)alloc((size_t)B_*N_*D_*2);
  float*    biasT  = (float*)alloc((size_t)N_*4);
  _Float16* Wt     = (_Float16*)alloc((size_t)832*128*2);
  float*    bcat   = (float*)alloc((size_t)832*4);
  _Float16* Uht    = (_Float16*)alloc((size_t)D_*DV_*2);
  _Float16* qh     = (_Float16*)alloc((size_t)B_*N_*DQK_*2);
  _Float16* kh     = (_Float16*)alloc((size_t)B_*N_*DQK_*2);
  _Float16* vT     = (_Float16*)alloc((size_t)B_*DV_*N_*2);
  float*    resetb = (float*)alloc((size_t)B_*N_*DV_*4);
  float*    updateb= (float*)alloc((size_t)B_*N_*D_*4);
  float*    hemab  = (float*)alloc((size_t)B_*N_*D_*4);
  _Float16* gatedh = (_Float16*)alloc((size_t)B_*N_*DV_*2);
  float*    attnp  = (float*)alloc((size_t)B_*2*288*64*128*4);

  prep_weights<<<416, 256, 0, stream>>>(Wqk, Wv, Wr, Wu, Wh, bqk, bv, br, bu, bh, Wt, bcat);
  prep_uh<<<128, 256, 0, stream>>>(Uh, Uht);
  bias_table<<<16, 256, 0, stream>>>(rel_table, biasT);
  ema_phase1<<<1024, 256, 0, stream>>>(x, expansion, alphas, dampen, F, xh);
  ema_carry<<<16, 256, 0, stream>>>(F, alphas, dampen, carry);
  ema_phase2<<<1024, 256, 0, stream>>>(x, expansion, reduction, alphas, dampen, carry, ema, emah);
  linear_mfma<<<128*13, 256, 0, stream>>>(emah, xh, Wt, bcat, gamma, beta,
                                          qh, kh, vT, resetb, updateb, hemab);
  attn_kernel<<<2048, 256, 0, stream>>>(qh, kh, vT, biasT, attnp);
  combine_gated<<<2048, 256, 0, stream>>>(attnp, resetb, gatedh);
  final_mfma<<<256, 256, 0, stream>>>(gatedh, Uht, hemab, updateb, x, out);
}

// Round 5
// 131.240 us; speedup vs baseline: 1.2388x; 1.2388x over previous
//
#include <hip/hip_runtime.h>
#include <cstdint>
#include <cmath>

#define B_ 2
#define N_ 4096
#define D_ 128
#define H_ 16
#define DQK_ 64
#define DV_ 256

typedef float    f4_t  __attribute__((ext_vector_type(4)));
typedef float    f16f  __attribute__((ext_vector_type(16)));
typedef _Float16 h4_t  __attribute__((ext_vector_type(4)));
typedef _Float16 h8_t  __attribute__((ext_vector_type(8)));

__device__ __forceinline__ float sigmoidf_(float z) { return 1.f/(1.f + expf(-z)); }
__device__ __forceinline__ float siluf_(float z)    { return z/(1.f + expf(-z)); }
__device__ __forceinline__ f16f zero16() {
  f16f z;
#pragma unroll
  for (int i = 0; i < 16; ++i) z[i] = 0.f;
  return z;
}

// ---------------- EMA: s[t] = q*s[t-1] + a*exp[h,d]*x[t], chunked scan ----------------
__global__ void ema_phase1(const float* __restrict__ x, const float* __restrict__ expansion,
                           const float* __restrict__ alphas, const float* __restrict__ dampen,
                           float* __restrict__ F, _Float16* __restrict__ xh) {
  int bid = blockIdx.x;
  int dg = bid & 7, c = (bid >> 3) & 63, b = bid >> 9;
  int h = threadIdx.x & 15, dl = threadIdx.x >> 4;
  int d = dg*16 + dl;
  float a  = sigmoidf_(alphas[h]);
  float dm = sigmoidf_(dampen[h]);
  float q  = (1.f - a)*dm;
  float coef = a * expansion[h*D_ + d];
  __shared__ float xs[64][16];
  {
    int e = threadIdx.x;
    int t = e >> 2, seg = e & 3;
    const float* xp = x + ((size_t)b*N_ + c*64 + t)*D_ + dg*16 + seg*4;
    f4_t v = *(const f4_t*)xp;
    *(f4_t*)&xs[t][seg*4] = v;
    h4_t hv;
#pragma unroll
    for (int j = 0; j < 4; ++j) hv[j] = (_Float16)v[j];
    *(h4_t*)(xh + ((size_t)b*N_ + c*64 + t)*D_ + dg*16 + seg*4) = hv;
  }
  __syncthreads();
  float s = 0.f;
#pragma unroll
  for (int t = 0; t < 64; ++t) s = fmaf(q, s, coef*xs[t][dl]);
  F[(((size_t)b*H_ + h)*D_ + d)*64 + c] = s;
}

__global__ void ema_carry(const float* __restrict__ F, const float* __restrict__ alphas,
                          const float* __restrict__ dampen, float* __restrict__ carry) {
  int idx = blockIdx.x*256 + threadIdx.x;
  int h = (idx >> 7) & 15;
  float a  = sigmoidf_(alphas[h]);
  float dm = sigmoidf_(dampen[h]);
  float q  = (1.f - a)*dm;
  float qL = q;
#pragma unroll
  for (int i = 0; i < 6; ++i) qL *= qL;
  const float* Fp = F + (size_t)idx*64;
  float* cp = carry + (size_t)idx*64;
  float s = 0.f;
  for (int cc = 0; cc < 64; ++cc) { cp[cc] = s; s = fmaf(qL, s, Fp[cc]); }
}

__global__ void ema_phase2(const float* __restrict__ x, const float* __restrict__ expansion,
                           const float* __restrict__ reduction,
                           const float* __restrict__ alphas, const float* __restrict__ dampen,
                           const float* __restrict__ carry, float* __restrict__ ema,
                           _Float16* __restrict__ emah) {
  int bid = blockIdx.x;
  int dg = bid & 7, c = (bid >> 3) & 63, b = bid >> 9;
  int h = threadIdx.x & 15, dl = threadIdx.x >> 4;
  int d = dg*16 + dl;
  float a  = sigmoidf_(alphas[h]);
  float dm = sigmoidf_(dampen[h]);
  float q  = (1.f - a)*dm;
  float coef = a * expansion[h*D_ + d];
  float red  = reduction[h*D_ + d];
  __shared__ float xs[64][16];
  {
    int e = threadIdx.x;
    int t = e >> 2, seg = e & 3;
    const float* xp = x + ((size_t)b*N_ + c*64 + t)*D_ + dg*16 + seg*4;
    *(f4_t*)&xs[t][seg*4] = *(const f4_t*)xp;
  }
  __syncthreads();
  float s = carry[(((size_t)b*H_ + h)*D_ + d)*64 + c];
  for (int t = 0; t < 64; ++t) {
    s = fmaf(q, s, coef*xs[t][dl]);
    float v = red * s;
    v += __shfl_xor(v, 1); v += __shfl_xor(v, 2);
    v += __shfl_xor(v, 4); v += __shfl_xor(v, 8);
    if (h == 0) {
      size_t o = ((size_t)b*N_ + c*64 + t)*D_ + d;
      ema[o] = v;
      emah[o] = (_Float16)v;
    }
  }
}

// ------- merged prep: Wt[832][128] f16 + bcat, Uht[128][256] f16, bias2T[4096] -------
// bias2T[d] = (8*table[bucket(d)] - mu) * 1.1283792  (t-space for sigmoid-poly CDF)
__global__ void prep_all(const float* __restrict__ Wqk, const float* __restrict__ Wv,
                         const float* __restrict__ Wr, const float* __restrict__ Wu,
                         const float* __restrict__ Wh,
                         const float* __restrict__ bqk, const float* __restrict__ bv,
                         const float* __restrict__ br, const float* __restrict__ bu,
                         const float* __restrict__ bh,
                         const float* __restrict__ Uh, const float* __restrict__ rel_table,
                         _Float16* __restrict__ Wt, float* __restrict__ bcat,
                         _Float16* __restrict__ Uht, float* __restrict__ bias2T) {
  int idx = blockIdx.x*256 + threadIdx.x;
  if (idx < 832*128) {
    int c = idx >> 7, d = idx & 127;
    const float* W; const float* bias; int ncol, cl;
    if (c < 64)       { W=Wqk; bias=bqk; ncol=64;  cl=c; }
    else if (c < 320) { W=Wv;  bias=bv;  ncol=256; cl=c-64; }
    else if (c < 576) { W=Wr;  bias=br;  ncol=256; cl=c-320; }
    else if (c < 704) { W=Wu;  bias=bu;  ncol=128; cl=c-576; }
    else              { W=Wh;  bias=bh;  ncol=128; cl=c-704; }
    Wt[idx] = (_Float16)W[d*ncol + cl];
    if (d == 0) bcat[c] = bias[cl];
  } else if (idx < 832*128 + 32768) {
    int i2 = idx - 832*128;
    int k = i2 >> 7, c = i2 & 127;
    Uht[(size_t)c*256 + k] = (_Float16)Uh[i2];
  } else if (idx < 832*128 + 32768 + 4096) {
    int r = idx - (832*128 + 32768);
    int bucket;
    if (r < 16) bucket = r;
    else {
      double v = log((double)r / 16.0) / log(8.0) * 16.0;
      bucket = 16 + (int)v;
      if (bucket > 31) bucket = 31;
    }
    bias2T[r] = (rel_table[bucket]*8.0f - 0.70710678f) * 1.1283792f;
  }
}

// ---------------- fused linears as MFMA GEMM: [8192 x 128] @ [128 x 832] ----------------
__global__ __launch_bounds__(256) void linear_mfma(
    const _Float16* __restrict__ emah, const _Float16* __restrict__ xh,
    const _Float16* __restrict__ Wt, const float* __restrict__ bcat,
    const float* __restrict__ gamma, const float* __restrict__ beta,
    _Float16* __restrict__ qh, _Float16* __restrict__ kh, _Float16* __restrict__ vT,
    float* __restrict__ resetb, float* __restrict__ updateb, float* __restrict__ hemab) {
  int slab = blockIdx.x % 13, rt = blockIdx.x / 13;
  int tid = threadIdx.x;
  int lane = tid & 63, w = tid >> 6;
  int lr = lane & 15, lg = lane >> 4;
  int mode = (slab==0)?0:(slab<5)?1:(slab<9)?2:(slab<11)?3:4;
  const _Float16* src = (mode==1) ? xh : emah;
  __shared__ _Float16 As[64][136];
  __shared__ _Float16 Ws[64][136];
  {
    const h8_t* s8 = (const h8_t*)(src + (size_t)rt*64*D_);
#pragma unroll
    for (int i = 0; i < 4; ++i) {
      int idx = tid + i*256;
      int row = idx >> 4, seg = idx & 15;
      *(h8_t*)&As[row][seg*8] = s8[idx];
    }
    const h8_t* w8 = (const h8_t*)(Wt + (size_t)slab*64*D_);
#pragma unroll
    for (int i = 0; i < 4; ++i) {
      int idx = tid + i*256;
      int row = idx >> 4, seg = idx & 15;
      *(h8_t*)&Ws[row][seg*8] = w8[idx];
    }
  }
  __syncthreads();
  h4_t af[8];
#pragma unroll
  for (int ks = 0; ks < 8; ++ks) af[ks] = *(const h4_t*)&As[w*16 + lr][ks*16 + lg*4];
  int row0 = rt*64 + w*16 + lg*4;
#pragma unroll
  for (int ns = 0; ns < 4; ++ns) {
    f4_t acc = (f4_t){0.f,0.f,0.f,0.f};
#pragma unroll
    for (int ks = 0; ks < 8; ++ks) {
      h4_t bf = *(const h4_t*)&Ws[ns*16 + lr][ks*16 + lg*4];
      acc = __builtin_amdgcn_mfma_f32_16x16x16f16(af[ks], bf, acc, 0, 0, 0);
    }
    int c = slab*64 + ns*16 + lr;
    float bias = bcat[c];
    if (mode == 0) {
      float g0 = gamma[c], g1 = gamma[64+c], be0 = beta[c], be1 = beta[64+c];
#pragma unroll
      for (int r = 0; r < 4; ++r) {
        float qk = siluf_(acc[r] + bias);
        size_t row = row0 + r;
        qh[row*DQK_ + c] = (_Float16)(qk*g0 + be0);
        kh[row*DQK_ + c] = (_Float16)(qk*g1 + be1);
      }
    } else if (mode == 1) {
      int cl = c - 64;
      int bb = row0 >> 12, rl = row0 & 4095;
      h4_t vv;
#pragma unroll
      for (int r = 0; r < 4; ++r) vv[r] = (_Float16)siluf_(acc[r] + bias);
      *(h4_t*)&vT[((size_t)bb*DV_ + cl)*N_ + rl] = vv;
    } else if (mode == 2) {
      int cl = c - 320;
#pragma unroll
      for (int r = 0; r < 4; ++r) resetb[(size_t)(row0 + r)*DV_ + cl] = siluf_(acc[r] + bias);
    } else if (mode == 3) {
      int cl = c - 576;
#pragma unroll
      for (int r = 0; r < 4; ++r) updateb[(size_t)(row0 + r)*D_ + cl] = sigmoidf_(acc[r] + bias);
    } else {
      int cl = c - 704;
#pragma unroll
      for (int r = 0; r < 4; ++r) hemab[(size_t)(row0 + r)*D_ + cl] = acc[r] + bias;
    }
  }
}

// ---------------- attention: laplacianCDF(QK^T/n + bias) @ V, causal, 32x32x8 MFMA -------
// grid 1024 = 64(it, largest-first) x 8(jsplit) x 2(b). block 256 = 4 waves = (ih, dvh).
// Swapped MFMA: S^T = mfma_32x32x8(K, Q); its C regs ARE the PV A-fragment (r = 4*ks+e).
// Double-buffered 32-j tiles, reg-staged; pads: K stride 68 f16, V stride 36 f16 (2-way max).
__global__ __launch_bounds__(256) void attn_kernel(
    const _Float16* __restrict__ qh, const _Float16* __restrict__ kh,
    const _Float16* __restrict__ vT, const float* __restrict__ bias2T,
    float* __restrict__ attnp) {
  int bid = blockIdx.x;
  int b = bid & 1;
  int s = (bid >> 1) & 7;
  int it = 63 - (bid >> 4);
  int q_ = it >> 3, r_ = it & 7;
  int nblk = q_ + 1;
  if (s >= nblk) return;
  int slot = 4*q_*(q_+1) + r_*(q_+1) + s;
  int i0 = it * 64;
  int jlo = 16*s;                           // 32-j units
  int jhi = min(16*s + 16, 2*it + 2);
  int nt = jhi - jlo;
  int tid = threadIdx.x;
  int lane = tid & 63, w = tid >> 6;
  int ih = w & 1, dvh = w >> 1;
  int lm = lane & 31, lg = lane >> 5;

  __shared__ __align__(16) char lds[2][22784];   // K [32][68]f16 @0 (4352B), V [256][36]f16 @4352
  __shared__ float biasW[576];

  // bias window for this block (t-space values)
  int jmax = jhi*32 - 1, jmin = jlo*32;
  int dlo = i0 - jmax;
  int cnt = 64 + jmax - jmin;
  for (int k = tid; k < cnt; k += 256) {
    int d = dlo + k; d = d < 0 ? 0 : (d > 4095 ? 4095 : d);
    biasW[k] = bias2T[d];
  }

  // Q fragments (B of QK): lane needs Q[i0+ih*32+lm][8*ksq + 4*lg + e]
  h4_t qf[8];
  {
    const _Float16* qp = qh + ((size_t)b*N_ + i0 + ih*32 + lm)*DQK_ + 4*lg;
#pragma unroll
    for (int ksq = 0; ksq < 8; ++ksq) qf[ksq] = *(const h4_t*)(qp + 8*ksq);
  }

  f16f accO[4];
#pragma unroll
  for (int i = 0; i < 4; ++i) accO[i] = zero16();

  const _Float16* kbase = kh + (size_t)b*N_*DQK_;
  const _Float16* vbase = vT + (size_t)b*DV_*N_;
  int kj = tid >> 3, kseg = tid & 7;        // K staging: row, 16B seg

  h4_t krA, krB, vr[8];
#define ISSUE_(J0F16) { \
  h8_t k8 = *(const h8_t*)(kbase + (size_t)((J0F16) + kj)*DQK_ + kseg*8); \
  krA = __builtin_shufflevector(k8, k8, 0,1,2,3); \
  krB = __builtin_shufflevector(k8, k8, 4,5,6,7); \
  _Pragma("unroll") for (int i = 0; i < 4; ++i) { \
    h8_t v8 = *(const h8_t*)(vbase + (size_t)tid*N_ + (J0F16) + i*8); \
    vr[2*i]   = __builtin_shufflevector(v8, v8, 0,1,2,3); \
    vr[2*i+1] = __builtin_shufflevector(v8, v8, 4,5,6,7); } }

#define COMMIT_(BUF) { \
  char* buf_ = (BUF); \
  char* ka_ = buf_ + kj*136 + kseg*16; \
  *(h4_t*)ka_ = krA; *(h4_t*)(ka_ + 8) = krB; \
  char* va_ = buf_ + 4352 + tid*72; \
  _Pragma("unroll") for (int i = 0; i < 4; ++i) { \
    *(h4_t*)(va_ + i*16) = vr[2*i]; *(h4_t*)(va_ + i*16 + 8) = vr[2*i+1]; } }

  ISSUE_(jlo*32); COMMIT_(lds[0]);
  __syncthreads();
  int cur = 0;
  const float C1 = 1.1283792f / 4096.f;
  int ibase = i0 + ih*32 + lm;
#pragma unroll 1
  for (int t = 0; t < nt; ++t) {
    int j032 = (jlo + t)*32;
    bool more = (t+1 < nt);
    if (more) ISSUE_((jlo + t + 1)*32);
    const char* kb = lds[cur];
    const char* vb = lds[cur] + 4352;
    // S^T = sum_k mfma(K_frag, Q_frag): rows j(0..31), cols i(0..31)
    f16f accS = zero16();
#pragma unroll
    for (int ksq = 0; ksq < 8; ++ksq) {
      h4_t kf = *(const h4_t*)(kb + lm*136 + 16*ksq + 8*lg);
      accS = __builtin_amdgcn_mfma_f32_32x32x8f16(kf, qf[ksq], accS, 0, 0, 0);
    }
    // P = sigmoid(poly(t)), t = accS*C1 + biasW;  reg r -> PV A-frag (ks=r>>2, e=r&3)
    h4_t pa[4];
    int jb = j032 + 4*lg;
#pragma unroll
    for (int rr = 0; rr < 16; ++rr) {
      int j = jb + 8*(rr>>2) + (rr&3);
      int delta = ibase - j;
      float tt = fmaf(accS[rr], C1, biasW[delta - dlo]);
      float y = tt*fmaf(tt*tt, 0.07056f, 1.5976f);
      float u = __expf(-y);
      float pv = __builtin_amdgcn_rcpf(1.f + u);
      pv = delta < 0 ? 0.f : pv;
      pa[rr>>2][rr&3] = (_Float16)pv;
    }
    // O += P @ V (this wave's dv half)
#pragma unroll
    for (int ks = 0; ks < 4; ++ks) {
#pragma unroll
      for (int dvb = 0; dvb < 4; ++dvb) {
        h4_t vf = *(const h4_t*)(vb + (dvh*128 + dvb*32 + lm)*72 + 16*ks + 8*lg);
        accO[dvb] = __builtin_amdgcn_mfma_f32_32x32x8f16(pa[ks], vf, accO[dvb], 0, 0, 0);
      }
    }
    if (more) COMMIT_(lds[cur^1]);
    __syncthreads();
    cur ^= 1;
  }
#undef ISSUE_
#undef COMMIT_

  float* op = attnp + ((size_t)b*288 + slot)*64*256;
#pragma unroll
  for (int dvb = 0; dvb < 4; ++dvb) {
    int col = dvh*128 + dvb*32 + lm;
#pragma unroll
    for (int rr = 0; rr < 16; ++rr) {
      int row = ih*32 + 8*(rr>>2) + 4*lg + (rr&3);
      op[(size_t)row*256 + col] = accO[dvb][rr];
    }
  }
}

// gatedh = (sum of valid attn partials) * reset, cast to f16
__global__ void combine_gated(const float* __restrict__ attnp, const float* __restrict__ resetb,
                              _Float16* __restrict__ gatedh) {
  size_t fi = (size_t)blockIdx.x*256 + threadIdx.x;   // f4 index over 8192*256
  int c4 = (int)(fi & 63);
  int rr = (int)(fi >> 6);
  int b = rr >> 12, n = rr & 4095;
  int it = n >> 6, rowLocal = n & 63;
  int q_ = it >> 3, r_ = it & 7;
  int nblk = q_ + 1;
  int base = 4*q_*(q_+1) + r_*(q_+1);
  const f4_t* ap = (const f4_t*)(attnp + (((size_t)b*288 + base)*64 + rowLocal)*256);
  f4_t acc = (f4_t){0.f,0.f,0.f,0.f};
  for (int s = 0; s < nblk; ++s)
    acc += ap[(size_t)s*4096 + c4];
  f4_t rg = ((const f4_t*)resetb)[fi];
  f4_t g = acc * rg;
  h4_t hg;
#pragma unroll
  for (int j = 0; j < 4; ++j) hg[j] = (_Float16)g[j];
  *(h4_t*)(gatedh + fi*4) = hg;
}

// ---------------- final: H = silu(hemab + gated@Uh); out = u*H + (1-u)*x ----------------
__global__ __launch_bounds__(256) void final_mfma(
    const _Float16* __restrict__ gatedh, const _Float16* __restrict__ Uht,
    const float* __restrict__ hemab, const float* __restrict__ updateb,
    const float* __restrict__ x, float* __restrict__ out) {
  int rt = blockIdx.x >> 1, cs = blockIdx.x & 1;
  int tid = threadIdx.x;
  int lane = tid & 63, w = tid >> 6;
  int lr = lane & 15, lg = lane >> 4;
  int row0 = rt*64, c0 = cs*64;
  __shared__ _Float16 As[64][136];
  __shared__ _Float16 Ws[64][136];
  f4_t acc[4];
#pragma unroll
  for (int ns = 0; ns < 4; ++ns) acc[ns] = (f4_t){0.f,0.f,0.f,0.f};
#pragma unroll
  for (int kc = 0; kc < 2; ++kc) {
    __syncthreads();
#pragma unroll
    for (int i = 0; i < 4; ++i) {
      int idx = tid + i*256;
      int row = idx >> 4, seg = idx & 15;
      *(h8_t*)&As[row][seg*8] =
          *(const h8_t*)(gatedh + (size_t)(row0 + row)*DV_ + kc*128 + seg*8);
      *(h8_t*)&Ws[row][seg*8] =
          *(const h8_t*)(Uht + (size_t)(c0 + row)*DV_ + kc*128 + seg*8);
    }
    __syncthreads();
    h4_t af[8];
#pragma unroll
    for (int ks = 0; ks < 8; ++ks) af[ks] = *(const h4_t*)&As[w*16 + lr][ks*16 + lg*4];
#pragma unroll
    for (int ns = 0; ns < 4; ++ns) {
#pragma unroll
      for (int ks = 0; ks < 8; ++ks) {
        h4_t bf = *(const h4_t*)&Ws[ns*16 + lr][ks*16 + lg*4];
        acc[ns] = __builtin_amdgcn_mfma_f32_16x16x16f16(af[ks], bf, acc[ns], 0, 0, 0);
      }
    }
  }
  int orow = row0 + w*16 + lg*4;
#pragma unroll
  for (int ns = 0; ns < 4; ++ns) {
    int col = c0 + ns*16 + lr;
#pragma unroll
    for (int r = 0; r < 4; ++r) {
      size_t o = (size_t)(orow + r)*D_ + col;
      float z = acc[ns][r] + hemab[o];
      float Hv = siluf_(z);
      float u  = updateb[o];
      out[o] = u*Hv + (1.f - u)*x[o];
    }
  }
}

extern "C" void kernel_launch(void* const* d_in, const int* in_sizes, int n_in,
                              void* d_out, int out_size, void* d_ws, size_t ws_size,
                              hipStream_t stream) {
  (void)in_sizes; (void)n_in; (void)out_size; (void)ws_size;
  const float* x         = (const float*)d_in[0];
  const float* expansion = (const float*)d_in[1];
  const float* reduction = (const float*)d_in[2];
  const float* alphas    = (const float*)d_in[3];
  const float* dampen    = (const float*)d_in[4];
  const float* Wqk       = (const float*)d_in[5];
  const float* bqk       = (const float*)d_in[6];
  const float* gamma     = (const float*)d_in[7];
  const float* beta      = (const float*)d_in[8];
  const float* Wv        = (const float*)d_in[9];
  const float* bv        = (const float*)d_in[10];
  const float* rel_table = (const float*)d_in[11];
  const float* Wr        = (const float*)d_in[12];
  const float* br        = (const float*)d_in[13];
  const float* Wu        = (const float*)d_in[14];
  const float* bu        = (const float*)d_in[15];
  const float* Wh        = (const float*)d_in[16];
  const float* Uh        = (const float*)d_in[17];
  const float* bh        = (const float*)d_in[18];
  float* out = (float*)d_out;

  char* p = (char*)d_ws;
  size_t off = 0;
  auto alloc = [&](size_t bytes) -> char* {
    char* r = p + off;
    off += (bytes + 255) & ~(size_t)255;
    return r;
  };
  float*    F      = (float*)alloc((size_t)B_*H_*D_*64*4);
  float*    carry  = (float*)alloc((size_t)B_*H_*D_*64*4);
  float*    ema    = (float*)alloc((size_t)B_*N_*D_*4);
  _Float16* emah   = (_Float16*)alloc((size_t)B_*N_*D_*2);
  _Float16* xh     = (_Float16*)alloc((size_t)B_*N_*D_*2);
  float*    bias2T = (float*)alloc((size_t)N_*4);
  _Float16* Wt     = (_Float16*)alloc((size_t)832*128*2);
  float*    bcat   = (float*)alloc((size_t)832*4);
  _Float16* Uht    = (_Float16*)alloc((size_t)D_*DV_*2);
  _Float16* qh     = (_Float16*)alloc((size_t)B_*N_*DQK_*2);
  _Float16* kh     = (_Float16*)alloc((size_t)B_*N_*DQK_*2);
  _Float16* vT     = (_Float16*)alloc((size_t)B_*DV_*N_*2);
  float*    resetb = (float*)alloc((size_t)B_*N_*DV_*4);
  float*    updateb= (float*)alloc((size_t)B_*N_*D_*4);
  float*    hemab  = (float*)alloc((size_t)B_*N_*D_*4);
  _Float16* gatedh = (_Float16*)alloc((size_t)B_*N_*DV_*2);
  float*    attnp  = (float*)alloc((size_t)B_*288*64*DV_*4);

  prep_all<<<560, 256, 0, stream>>>(Wqk, Wv, Wr, Wu, Wh, bqk, bv, br, bu, bh,
                                    Uh, rel_table, Wt, bcat, Uht, bias2T);
  ema_phase1<<<1024, 256, 0, stream>>>(x, expansion, alphas, dampen, F, xh);
  ema_carry<<<16, 256, 0, stream>>>(F, alphas, dampen, carry);
  ema_phase2<<<1024, 256, 0, stream>>>(x, expansion, reduction, alphas, dampen, carry, ema, emah);
  linear_mfma<<<128*13, 256, 0, stream>>>(emah, xh, Wt, bcat, gamma, beta,
                                          qh, kh, vT, resetb, updateb, hemab);
  attn_kernel<<<1024, 256, 0, stream>>>(qh, kh, vT, bias2T, attnp);
  combine_gated<<<2048, 256, 0, stream>>>(attnp, resetb, gatedh);
  final_mfma<<<256, 256, 0, stream>>>(gatedh, Uht, hemab, updateb, x, out);
}